// Round 5
// baseline (4995.560 us; speedup 1.0000x reference)
//
#include <hip/hip_runtime.h>

// GRU B=64 S=512 I=512 H=1024 — fp32 inputs, FP32 output (reference dtypes;
// harness rule: output dtype = reference output dtype = float32).
// Persistent weight-stationary kernel, regular launch.
//  - 256 WGs (1 resident/CU by capacity) = 4 batch-groups x 64 CUs;
//    each CU owns 16 batches x 16 dims.
//  - W_hh+W_ih converted fp32->bf16 once at startup, held in VGPRs (144/lane).
//  - per step: MFMA 16x16x32 bf16 (A = h/x, B = weights), K split across the
//    4 waves, LDS reduce, fp32 gate math, h state fp32 in registers.
//  - h exchanged as bf16 via ws ping-pong; stores = packed agent atomics,
//    then release fence -> counter fetch_add -> spin -> acquire fence;
//    loads = agent relaxed atomics (cannot be compiler-cached, bypass stale L1/L2).
// ws: [0,256KB) h ping-pong bf16; +8KB barrier counters.

#define B_ 64
#define S_ 512
#define I_ 512
#define H_ 1024

typedef short short8 __attribute__((ext_vector_type(8)));
typedef float f32x4 __attribute__((ext_vector_type(4)));
typedef unsigned long long u64x2 __attribute__((ext_vector_type(2)));

__device__ __forceinline__ unsigned short f2bf(float f) {
    unsigned u = __builtin_bit_cast(unsigned, f);
    u += 0x7fffu + ((u >> 16) & 1u);
    return (unsigned short)(u >> 16);
}
__device__ __forceinline__ float sigm(float x) { return 1.f / (1.f + __expf(-x)); }
__device__ __forceinline__ float tanh_(float x) { return 2.f / (1.f + __expf(-2.f * x)) - 1.f; }

__device__ __forceinline__ f32x4 MFMA(short8 a, short8 b, f32x4 c) {
    return __builtin_amdgcn_mfma_f32_16x16x32_bf16(a, b, c, 0, 0, 0);
}

// 8 consecutive fp32 -> bf16 short8 (RNE)
__device__ __forceinline__ short8 load8bf(const float* p) {
    float4 a = *(const float4*)p;
    float4 b = *(const float4*)(p + 4);
    short8 r;
    r[0] = (short)f2bf(a.x); r[1] = (short)f2bf(a.y); r[2] = (short)f2bf(a.z); r[3] = (short)f2bf(a.w);
    r[4] = (short)f2bf(b.x); r[5] = (short)f2bf(b.y); r[6] = (short)f2bf(b.z); r[7] = (short)f2bf(b.w);
    return r;
}

__launch_bounds__(256, 1)
__global__ void gru_persistent(const float* __restrict__ xin,            // [B,S,I] fp32
                               unsigned short* hbase,                    // ws ping-pong bf16
                               unsigned* cnt,
                               const float* __restrict__ w_ih,           // [3H,I] fp32
                               const float* __restrict__ w_hh,           // [3H,H] fp32
                               const float* __restrict__ b_ihp,          // [3H] fp32
                               const float* __restrict__ b_hhp,          // [3H] fp32
                               const float* __restrict__ h0,             // [B,H] fp32
                               float* __restrict__ out) {                // fp32 [B,S,H]+[B,H]
    const int tid = threadIdx.x;
    const int w = tid >> 6;        // wave id: K-slice owner
    const int l = tid & 63;
    const int ln = l & 15;         // A-frag: batch row / B-frag: dim col
    const int lq = l >> 4;         // quad -> k sub-offset
    const int grp = blockIdx.x & 3;      // batch group (16 batches)
    const int cu  = blockIdx.x >> 2;     // dim slice  (16 dims)
    const int b0 = grp * 16, d0 = cu * 16;

    // ---- startup: weight B-fragments fp32 -> bf16 -> VGPRs ----
    // B-layout: lane ln holds output-row (n) = d0+ln; k = k_base + lq*8 + j
    short8 Whr[8], Whz[8], Whn[8], Wir[4], Wiz[4], Win[4];
    {
        const int nrow = d0 + ln;
        #pragma unroll
        for (int f = 0; f < 8; ++f) {
            int k = w * 256 + f * 32 + lq * 8;
            Whr[f] = load8bf(w_hh + (size_t)(0 * H_ + nrow) * H_ + k);
            Whz[f] = load8bf(w_hh + (size_t)(1 * H_ + nrow) * H_ + k);
            Whn[f] = load8bf(w_hh + (size_t)(2 * H_ + nrow) * H_ + k);
        }
        #pragma unroll
        for (int f = 0; f < 4; ++f) {
            int k = w * 128 + f * 32 + lq * 8;
            Wir[f] = load8bf(w_ih + (size_t)(0 * H_ + nrow) * I_ + k);
            Wiz[f] = load8bf(w_ih + (size_t)(1 * H_ + nrow) * I_ + k);
            Win[f] = load8bf(w_ih + (size_t)(2 * H_ + nrow) * I_ + k);
        }
    }

    // ---- per-thread elementwise assignment: (m_t = batch, n_t = dim) ----
    const int n_t = tid & 15, m_t = tid >> 4;
    const int d = d0 + n_t;
    const float b_r  = b_ihp[d]          + b_hhp[d];
    const float b_z  = b_ihp[H_ + d]     + b_hhp[H_ + d];
    const float b_in = b_ihp[2 * H_ + d];
    const float b_hn = b_hhp[2 * H_ + d];
    float hprev = h0[(size_t)(b0 + m_t) * H_ + d];   // fp32 state in register

    __shared__ float red[4 * 4 * 16 * 20];           // [gate][wave][n16][m pad20]

    const int ha_base = (b0 + ln) * H_ + w * 256 + lq * 8;        // + f*32 (shorts)
    const float* xrow = xin + (size_t)(b0 + ln) * S_ * I_ + w * 128 + lq * 8;

    for (int t = 0; t < S_; ++t) {
        unsigned short* hnx = hbase + (size_t)((t + 1) & 1) * (B_ * H_);

        // A-fragments: h (bf16 ping-pong via agent atomics, or fp32 h0 at t=0)
        short8 hA[8], xA[4];
        if (t == 0) {
            #pragma unroll
            for (int f = 0; f < 8; ++f)
                hA[f] = load8bf(h0 + (size_t)(b0 + ln) * H_ + w * 256 + f * 32 + lq * 8);
        } else {
            const unsigned short* hc = hbase + (size_t)(t & 1) * (B_ * H_);
            #pragma unroll
            for (int f = 0; f < 8; ++f) {
                unsigned long long* p = (unsigned long long*)(hc + ha_base + f * 32);
                u64x2 v;
                v[0] = __hip_atomic_load(p,     __ATOMIC_RELAXED, __HIP_MEMORY_SCOPE_AGENT);
                v[1] = __hip_atomic_load(p + 1, __ATOMIC_RELAXED, __HIP_MEMORY_SCOPE_AGENT);
                hA[f] = __builtin_bit_cast(short8, v);
            }
        }
        const float* xp = xrow + (size_t)t * I_;
        #pragma unroll
        for (int f = 0; f < 4; ++f) xA[f] = load8bf(xp + f * 32);

        f32x4 ar = {0,0,0,0}, az = {0,0,0,0}, anh = {0,0,0,0}, anx = {0,0,0,0};
        #pragma unroll
        for (int f = 0; f < 8; ++f) {
            ar  = MFMA(hA[f], Whr[f], ar);
            az  = MFMA(hA[f], Whz[f], az);
            anh = MFMA(hA[f], Whn[f], anh);
        }
        #pragma unroll
        for (int f = 0; f < 4; ++f) {
            ar  = MFMA(xA[f], Wir[f], ar);
            az  = MFMA(xA[f], Wiz[f], az);
            anx = MFMA(xA[f], Win[f], anx);
        }

        // partials -> LDS. D layout: col(n) = lane&15, row(m) = quad*4+reg
        {
            int rbase = (w * 16 + ln) * 20 + lq * 4;
            *(f32x4*)&red[rbase]        = ar;
            *(f32x4*)&red[rbase + 1280] = az;
            *(f32x4*)&red[rbase + 2560] = anh;
            *(f32x4*)&red[rbase + 3840] = anx;
        }
        __syncthreads();

        // reduce over 4 waves (one (m_t,n_t) per thread)
        float rp = 0.f, zp = 0.f, nhp = 0.f, nxp = 0.f;
        #pragma unroll
        for (int ww = 0; ww < 4; ++ww) {
            int ib = (ww * 16 + n_t) * 20 + m_t;
            rp  += red[ib];
            zp  += red[ib + 1280];
            nhp += red[ib + 2560];
            nxp += red[ib + 3840];
        }
        float r = sigm(rp + b_r);
        float z = sigm(zp + b_z);
        float nn = tanh_(nxp + b_in + r * (nhp + b_hn));
        float h = nn + z * (hprev - nn);   // (1-z)*n + z*h
        hprev = h;

        // FP32 output [B,S,H] (+ final h [B,H] appended), coalesced over n_t
        out[((size_t)(b0 + m_t) * S_ + t) * H_ + d] = h;
        if (t == S_ - 1)
            out[(size_t)B_ * S_ * H_ + (size_t)(b0 + m_t) * H_ + d] = h;

        // h exchange: bf16 pairs packed across adjacent lanes, agent store
        {
            unsigned hb16 = f2bf(h);
            unsigned ob = (unsigned)__shfl_xor((int)hb16, 1, 64);
            if ((tid & 1) == 0) {
                unsigned packed = (hb16 & 0xffffu) | (ob << 16);
                __hip_atomic_store((unsigned*)(hnx + (size_t)(b0 + m_t) * H_ + d),
                                   packed, __ATOMIC_RELAXED, __HIP_MEMORY_SCOPE_AGENT);
            }
        }

        if (t < S_ - 1) {
            __syncthreads();  // drains vmcnt: all waves' h stores done
            if (tid == 0) {
                unsigned idx = (unsigned)grp * 512u + (unsigned)t;
                __builtin_amdgcn_fence(__ATOMIC_RELEASE, "agent");
                __hip_atomic_fetch_add(&cnt[idx], 1u, __ATOMIC_RELAXED, __HIP_MEMORY_SCOPE_AGENT);
                int guard = 0;
                while (__hip_atomic_load(&cnt[idx], __ATOMIC_RELAXED, __HIP_MEMORY_SCOPE_AGENT) < 64u) {
                    __builtin_amdgcn_s_sleep(1);
                    if (++guard > (1 << 22)) break;   // safety valve vs infinite hang
                }
                __builtin_amdgcn_fence(__ATOMIC_ACQUIRE, "agent");
            }
            __syncthreads();
        }
    }
}

extern "C" void kernel_launch(void* const* d_in, const int* in_sizes, int n_in,
                              void* d_out, int out_size, void* d_ws, size_t ws_size,
                              hipStream_t stream) {
    const float* xin  = (const float*)d_in[0];   // fp32 [B,S,I]
    const float* h0   = (const float*)d_in[1];   // fp32 [1,B,H]
    const float* w_ih = (const float*)d_in[2];   // fp32 [3H,I]
    const float* w_hh = (const float*)d_in[3];   // fp32 [3H,H]
    const float* b_ih = (const float*)d_in[4];   // fp32 [3H]
    const float* b_hh = (const float*)d_in[5];   // fp32 [3H]
    // size-based disambiguation (w_ih: 3H*I elems, w_hh: 3H*H)
    if (n_in >= 4 && in_sizes[2] == 3 * H_ * H_ && in_sizes[3] == 3 * H_ * I_) {
        const float* tmp = w_ih; w_ih = w_hh; w_hh = tmp;
    }
    float* out = (float*)d_out;                  // fp32 outputs + hn

    unsigned short* hb = (unsigned short*)d_ws;                   // 2 x B*H bf16
    unsigned* cnt = (unsigned*)(hb + 2 * (size_t)B_ * H_);        // 2048 u32

    // barrier counters must be zeroed every launch (ws is re-poisoned to 0xAA)
    hipMemsetAsync(cnt, 0, 2048 * sizeof(unsigned), stream);

    hipLaunchKernelGGL(gru_persistent, dim3(256), dim3(256), 0, stream,
                       xin, hb, cnt, w_ih, w_hh, b_ih, b_hh, h0, out);
}